// Round 1
// baseline (552.230 us; speedup 1.0000x reference)
//
#include <hip/hip_runtime.h>

#define B_    1024
#define NG_   32
#define F_    16
#define ED_   6
#define EG_   256
#define ET_   262144
#define H1_   5
#define C1_   80
#define HC1_  400
#define C2_   160
#define OBS_  512

#define S1_   408   // bf16 element stride for 400-wide node rows (816B, 16B-aligned, 8 bank-groups)
#define MSG_S 161

typedef unsigned short ushort8v __attribute__((ext_vector_type(8)));

__device__ __forceinline__ float bf2f(unsigned short u) {
  return __uint_as_float(((unsigned int)u) << 16);
}
__device__ __forceinline__ unsigned short f2bf(float f) {
  unsigned int u = __float_as_uint(f);
  u = u + 0x7FFFu + ((u >> 16) & 1u);   // RNE
  return (unsigned short)(u >> 16);
}

// ---------------------------------------------------------------------------
// Kernel A: one block per graph. Both GATv2 layers fully in LDS; layer 2 only
// evaluated for edges into the ego node (node 0 of the graph). Writes the
// ego hidden vector h2[160] per graph to workspace.
// ---------------------------------------------------------------------------
__global__ __launch_bounds__(256, 2)
void gnn_two_layer_kernel(
    const float* __restrict__ x, const int* __restrict__ eidx,
    const float* __restrict__ eattr,
    const float* __restrict__ Wl1, const float* __restrict__ bl1,
    const float* __restrict__ Wr1, const float* __restrict__ br1,
    const float* __restrict__ We1, const float* __restrict__ att1,
    const float* __restrict__ bc1,
    const float* __restrict__ Wl2, const float* __restrict__ bl2,
    const float* __restrict__ Wr2, const float* __restrict__ br2,
    const float* __restrict__ We2, const float* __restrict__ att2,
    const float* __restrict__ bc2,
    float* __restrict__ egoH)
{
  __shared__ unsigned short xl[NG_ * S1_];    // layer-1 source transform (message), bf16
  __shared__ unsigned short xrh[NG_ * S1_];   // layer-1 target transform, then reused as h
  __shared__ float sc[EG_ * H1_];             // scores -> alpha
  __shared__ float ea[EG_ * ED_];
  __shared__ int   esrc[EG_], edst[EG_];
  __shared__ int   eorder[EG_];
  __shared__ int   bstart[NG_ + 1];
  __shared__ float xloc[NG_ * F_];
  __shared__ float msg[8 * MSG_S];
  __shared__ float out2[C2_], xr2v[C2_];
  __shared__ float sArr[8], wArr[8];
  __shared__ float mrun_s, denrun_s, scale_s;

  const int b   = blockIdx.x;
  const int tid = threadIdx.x;
  const int n0  = b * NG_;
  const int eb  = b * EG_;

  // ---------------- phase 1: loads ----------------
  for (int i = tid; i < NG_ * F_; i += 256) xloc[i] = x[n0 * F_ + i];
  {
    const int e = tid;                         // blockDim == EG_
    esrc[e] = eidx[eb + e] - n0;
    edst[e] = eidx[ET_ + eb + e] - n0;
  }
  for (int i = tid; i < EG_ * ED_; i += 256) ea[i] = eattr[eb * ED_ + i];
  __syncthreads();

  // ---------------- phase 2: node transforms xl = xWl^T+bl, xr = xWr^T+br ----
  {
    const int n = tid & 31;
    float xv[16];
#pragma unroll
    for (int q = 0; q < 4; ++q) {
      float4 t = *(const float4*)(&xloc[n * F_ + q * 4]);
      xv[q * 4 + 0] = t.x; xv[q * 4 + 1] = t.y; xv[q * 4 + 2] = t.z; xv[q * 4 + 3] = t.w;
    }
    for (int o = (tid >> 5); o < 50; o += 8) {   // 50 octs of 8 channels
      const int c = o * 8;
      ushort8v hl, hr;
#pragma unroll
      for (int u = 0; u < 8; ++u) {
        const int cc = c + u;
        float aL = bl1[cc], aR = br1[cc];
        const float* wl = &Wl1[cc * F_];
        const float* wr = &Wr1[cc * F_];
#pragma unroll
        for (int k = 0; k < 16; ++k) {
          aL = fmaf(xv[k], wl[k], aL);
          aR = fmaf(xv[k], wr[k], aR);
        }
        hl[u] = f2bf(aL);
        hr[u] = f2bf(aR);
      }
      *(ushort8v*)(&xl[n * S1_ + c])  = hl;
      *(ushort8v*)(&xrh[n * S1_ + c]) = hr;
    }
  }
  __syncthreads();

  // ---------------- phase 3: edge scores (thread = edge) ----------------
  {
    const int e  = tid;
    const int sl = esrc[e], dl = edst[e];
    const float e0 = ea[e*ED_+0], e1 = ea[e*ED_+1], e2 = ea[e*ED_+2];
    const float e3 = ea[e*ED_+3], e4 = ea[e*ED_+4], e5 = ea[e*ED_+5];
    const unsigned short* xlrow = &xl[sl * S1_];
    const unsigned short* xrrow = &xrh[dl * S1_];
#pragma unroll
    for (int h = 0; h < H1_; ++h) {
      float sh = 0.f;
      for (int co = 0; co < 10; ++co) {
        const int c = h * C1_ + co * 8;
        ushort8v av = *(const ushort8v*)(xlrow + c);
        ushort8v rv = *(const ushort8v*)(xrrow + c);
#pragma unroll
        for (int u = 0; u < 8; ++u) {
          const int cc = c + u;
          float et = We1[cc*ED_+0]*e0 + We1[cc*ED_+1]*e1 + We1[cc*ED_+2]*e2
                   + We1[cc*ED_+3]*e3 + We1[cc*ED_+4]*e4 + We1[cc*ED_+5]*e5;
          float p = bf2f(av[u]) + bf2f(rv[u]) + et;
          p = (p > 0.f) ? p : 0.2f * p;
          sh = fmaf(p, att1[cc], sh);
        }
      }
      sc[e * H1_ + h] = sh;
    }
  }
  __syncthreads();

  // ---------------- phase 4: deterministic buckets by dst ----------------
  if (tid < NG_) {
    int cnt = 0;
    for (int e = 0; e < EG_; ++e) cnt += (edst[e] == tid);
    bstart[tid + 1] = cnt;
  }
  __syncthreads();
  if (tid == 0) {
    bstart[0] = 0;
    for (int d = 0; d < NG_; ++d) bstart[d + 1] += bstart[d];
  }
  __syncthreads();
  if (tid < NG_) {
    int p = bstart[tid];
    for (int e = 0; e < EG_; ++e)
      if (edst[e] == tid) eorder[p++] = e;
  }
  __syncthreads();

  // ---------------- phase 5: segment softmax per (dst, head) ----------------
  if (tid < NG_ * H1_) {
    const int d = tid & 31, h = tid >> 5;
    const int s0 = bstart[d], s1 = bstart[d + 1];
    float m = -INFINITY;
    for (int k = s0; k < s1; ++k) m = fmaxf(m, sc[eorder[k] * H1_ + h]);
    float den = 0.f;
    for (int k = s0; k < s1; ++k) {
      float t = expf(sc[eorder[k] * H1_ + h] - m);
      den += t;
      sc[eorder[k] * H1_ + h] = t;
    }
    const float r = 1.f / (den + 1e-16f);
    for (int k = s0; k < s1; ++k) sc[eorder[k] * H1_ + h] *= r;
  }
  __syncthreads();

  // ---------------- phase 6: aggregation, h = relu(sum alpha*msg + bc1) ------
  for (int idx = tid; idx < NG_ * 50; idx += 256) {
    const int d  = idx / 50;
    const int co = idx - d * 50;
    const int c  = co * 8;
    const int h  = c / C1_;           // oct never crosses a head (8 | 80)
    const int s0 = bstart[d], s1 = bstart[d + 1];
    float acc[8] = {0.f,0.f,0.f,0.f,0.f,0.f,0.f,0.f};
    for (int k = s0; k < s1; ++k) {
      const int e = eorder[k];
      const float al = sc[e * H1_ + h];
      ushort8v xv = *(const ushort8v*)(&xl[esrc[e] * S1_ + c]);
#pragma unroll
      for (int u = 0; u < 8; ++u) acc[u] = fmaf(al, bf2f(xv[u]), acc[u]);
    }
    ushort8v hv;
#pragma unroll
    for (int u = 0; u < 8; ++u)
      hv[u] = f2bf(fmaxf(acc[u] + bc1[c + u], 0.f));
    *(ushort8v*)(&xrh[d * S1_ + c]) = hv;   // xr dead; reuse as h (layer-1 out)
  }
  __syncthreads();

  // ---------------- phase 7: layer-2, ego node only ----------------
  const int nE = bstart[1];   // edges with local dst == 0 occupy eorder[0..nE)

  if (tid < C2_) {
    float acc = br2[tid];
    const float* wr = &Wr2[tid * HC1_];
    for (int k = 0; k < HC1_; k += 8) {
      ushort8v hv = *(const ushort8v*)(&xrh[k]);      // h[ego]
      float4 w0 = *(const float4*)(wr + k);
      float4 w1 = *(const float4*)(wr + k + 4);
      acc = fmaf(bf2f(hv[0]), w0.x, acc);
      acc = fmaf(bf2f(hv[1]), w0.y, acc);
      acc = fmaf(bf2f(hv[2]), w0.z, acc);
      acc = fmaf(bf2f(hv[3]), w0.w, acc);
      acc = fmaf(bf2f(hv[4]), w1.x, acc);
      acc = fmaf(bf2f(hv[5]), w1.y, acc);
      acc = fmaf(bf2f(hv[6]), w1.z, acc);
      acc = fmaf(bf2f(hv[7]), w1.w, acc);
    }
    xr2v[tid] = acc;
    out2[tid] = 0.f;
  }
  if (tid == 0) { mrun_s = -INFINITY; denrun_s = 0.f; scale_s = 0.f; }
  __syncthreads();

  for (int ch = 0; ch < nE; ch += 8) {
    const int nc = min(8, nE - ch);
    // messages msg[j][c] = Wl2 @ h[src_j] + bl2
    for (int idx = tid; idx < nc * C2_; idx += 256) {
      const int j  = idx / C2_;
      const int cc = idx - j * C2_;
      const int e  = eorder[ch + j];
      const unsigned short* hrow = &xrh[esrc[e] * S1_];
      const float* wl = &Wl2[cc * HC1_];
      float acc = bl2[cc];
      for (int k = 0; k < HC1_; k += 8) {
        ushort8v hv = *(const ushort8v*)(hrow + k);
        float4 w0 = *(const float4*)(wl + k);
        float4 w1 = *(const float4*)(wl + k + 4);
        acc = fmaf(bf2f(hv[0]), w0.x, acc);
        acc = fmaf(bf2f(hv[1]), w0.y, acc);
        acc = fmaf(bf2f(hv[2]), w0.z, acc);
        acc = fmaf(bf2f(hv[3]), w0.w, acc);
        acc = fmaf(bf2f(hv[4]), w1.x, acc);
        acc = fmaf(bf2f(hv[5]), w1.y, acc);
        acc = fmaf(bf2f(hv[6]), w1.z, acc);
        acc = fmaf(bf2f(hv[7]), w1.w, acc);
      }
      msg[j * MSG_S + cc] = acc;
    }
    __syncthreads();
    // per-edge score
    if (tid < nc) {
      const int e = eorder[ch + tid];
      const float e0 = ea[e*ED_+0], e1 = ea[e*ED_+1], e2 = ea[e*ED_+2];
      const float e3 = ea[e*ED_+3], e4 = ea[e*ED_+4], e5 = ea[e*ED_+5];
      float s = 0.f;
      for (int cc = 0; cc < C2_; ++cc) {
        float et = We2[cc*ED_+0]*e0 + We2[cc*ED_+1]*e1 + We2[cc*ED_+2]*e2
                 + We2[cc*ED_+3]*e3 + We2[cc*ED_+4]*e4 + We2[cc*ED_+5]*e5;
        float p = msg[tid * MSG_S + cc] + xr2v[cc] + et;
        p = (p > 0.f) ? p : 0.2f * p;
        s = fmaf(p, att2[cc], s);
      }
      sArr[tid] = s;
    }
    __syncthreads();
    // online softmax bookkeeping
    if (tid == 0) {
      float m = mrun_s;
      for (int j = 0; j < nc; ++j) m = fmaxf(m, sArr[j]);
      const float scl = expf(mrun_s - m);    // expf(-inf)=0 on first chunk
      float den = denrun_s * scl;
      for (int j = 0; j < nc; ++j) { float w = expf(sArr[j] - m); wArr[j] = w; den += w; }
      mrun_s = m; denrun_s = den; scale_s = scl;
    }
    __syncthreads();
    if (tid < C2_) {
      float o = out2[tid] * scale_s;
      for (int j = 0; j < nc; ++j) o = fmaf(wArr[j], msg[j * MSG_S + tid], o);
      out2[tid] = o;
    }
    __syncthreads();
  }

  if (tid < C2_) {
    const float v = out2[tid] / (denrun_s + 1e-16f) + bc2[tid];
    egoH[b * C2_ + tid] = fmaxf(v, 0.f);
  }
}

// ---------------------------------------------------------------------------
// Kernel B: dense head + MLP, 8 graphs per block.
// ---------------------------------------------------------------------------
__global__ __launch_bounds__(256, 2)
void mlp_head_kernel(
    const float* __restrict__ egoH,
    const float* __restrict__ Wd1, const float* __restrict__ bd1,
    const float* __restrict__ Wd2, const float* __restrict__ bd2,
    const float* __restrict__ Wf1, const float* __restrict__ bf1,
    const float* __restrict__ Wf2, const float* __restrict__ bf2,
    const float* __restrict__ Wm,  const float* __restrict__ bm,
    const float* __restrict__ Ws,  const float* __restrict__ bs,
    float* __restrict__ out)
{
  __shared__ float hE[8 * C2_];
  __shared__ float t1[8 * NG_];
  __shared__ float dbuf[8 * OBS_];
  __shared__ float f1b[8 * 256];
  __shared__ float f2b[8 * 257];   // padded stride: head stage reads stride-g

  const int g0  = blockIdx.x * 8;
  const int tid = threadIdx.x;

  for (int i = tid; i < 8 * C2_; i += 256) hE[i] = egoH[g0 * C2_ + i];
  __syncthreads();

  // t1 = ego @ Wd1^T + bd1   [8][32]
  {
    const int g = tid >> 5, o = tid & 31;
    float acc = bd1[o];
    const float* w  = &Wd1[o * C2_];
    const float* hp = &hE[g * C2_];
    for (int k = 0; k < C2_; k += 4) {
      float4 hv = *(const float4*)(hp + k);
      float4 wv = *(const float4*)(w + k);
      acc = fmaf(hv.x, wv.x, acc); acc = fmaf(hv.y, wv.y, acc);
      acc = fmaf(hv.z, wv.z, acc); acc = fmaf(hv.w, wv.w, acc);
    }
    t1[g * NG_ + o] = acc;
  }
  __syncthreads();

  // d = tanh(t1 @ Wd2^T + bd2)   [8][512]
  for (int idx = tid; idx < 8 * OBS_; idx += 256) {
    const int g = idx >> 9, o = idx & 511;
    float acc = bd2[o];
    const float* w  = &Wd2[o * NG_];
    const float* tp = &t1[g * NG_];
#pragma unroll
    for (int k = 0; k < NG_; k += 4) {
      float4 tv = *(const float4*)(tp + k);
      float4 wv = *(const float4*)(w + k);
      acc = fmaf(tv.x, wv.x, acc); acc = fmaf(tv.y, wv.y, acc);
      acc = fmaf(tv.z, wv.z, acc); acc = fmaf(tv.w, wv.w, acc);
    }
    dbuf[idx] = tanhf(acc);
  }
  __syncthreads();

  // f1 = relu(d @ Wf1^T + bf1)  [8][256], two outputs per thread
  for (int idx = tid; idx < 8 * 128; idx += 256) {
    const int g = idx >> 7, op = idx & 127, o = op * 2;
    float a0 = bf1[o], a1 = bf1[o + 1];
    const float* w0 = &Wf1[o * OBS_];
    const float* w1 = w0 + OBS_;
    const float* dp = &dbuf[g * OBS_];
    for (int k = 0; k < OBS_; k += 4) {
      float4 dv  = *(const float4*)(dp + k);
      float4 wv0 = *(const float4*)(w0 + k);
      float4 wv1 = *(const float4*)(w1 + k);
      a0 = fmaf(dv.x, wv0.x, a0); a0 = fmaf(dv.y, wv0.y, a0);
      a0 = fmaf(dv.z, wv0.z, a0); a0 = fmaf(dv.w, wv0.w, a0);
      a1 = fmaf(dv.x, wv1.x, a1); a1 = fmaf(dv.y, wv1.y, a1);
      a1 = fmaf(dv.z, wv1.z, a1); a1 = fmaf(dv.w, wv1.w, a1);
    }
    f1b[g * 256 + o]     = fmaxf(a0, 0.f);
    f1b[g * 256 + o + 1] = fmaxf(a1, 0.f);
  }
  __syncthreads();

  // f2 = relu(f1 @ Wf2^T + bf2)  [8][256]
  for (int idx = tid; idx < 8 * 128; idx += 256) {
    const int g = idx >> 7, op = idx & 127, o = op * 2;
    float a0 = bf2[o], a1 = bf2[o + 1];
    const float* w0 = &Wf2[o * 256];
    const float* w1 = w0 + 256;
    const float* fp = &f1b[g * 256];
    for (int k = 0; k < 256; k += 4) {
      float4 dv  = *(const float4*)(fp + k);
      float4 wv0 = *(const float4*)(w0 + k);
      float4 wv1 = *(const float4*)(w1 + k);
      a0 = fmaf(dv.x, wv0.x, a0); a0 = fmaf(dv.y, wv0.y, a0);
      a0 = fmaf(dv.z, wv0.z, a0); a0 = fmaf(dv.w, wv0.w, a0);
      a1 = fmaf(dv.x, wv1.x, a1); a1 = fmaf(dv.y, wv1.y, a1);
      a1 = fmaf(dv.z, wv1.z, a1); a1 = fmaf(dv.w, wv1.w, a1);
    }
    f2b[g * 257 + o]     = fmaxf(a0, 0.f);
    f2b[g * 257 + o + 1] = fmaxf(a1, 0.f);
  }
  __syncthreads();

  // heads: mean, log_std
  if (tid < 16) {
    const int g = tid >> 1, a = tid & 1;
    float am = bm[a], asv = bs[a];
    const float* fp = &f2b[g * 257];
    const float* wm = &Wm[a * 256];
    const float* ws = &Ws[a * 256];
    for (int k = 0; k < 256; ++k) {
      const float fv = fp[k];
      am  = fmaf(fv, wm[k], am);
      asv = fmaf(fv, ws[k], asv);
    }
    out[(g0 + g) * 2 + a]        = am;
    out[2048 + (g0 + g) * 2 + a] = -5.0f + 3.5f * (tanhf(asv) + 1.0f);
  }
}

extern "C" void kernel_launch(void* const* d_in, const int* in_sizes, int n_in,
                              void* d_out, int out_size, void* d_ws, size_t ws_size,
                              hipStream_t stream) {
  const float* x     = (const float*)d_in[0];
  const int*   eidx  = (const int*)d_in[1];
  const float* eattr = (const float*)d_in[2];
  const float* Wl1 = (const float*)d_in[3];  const float* bl1 = (const float*)d_in[4];
  const float* Wr1 = (const float*)d_in[5];  const float* br1 = (const float*)d_in[6];
  const float* We1 = (const float*)d_in[7];  const float* att1= (const float*)d_in[8];
  const float* bc1 = (const float*)d_in[9];
  const float* Wl2 = (const float*)d_in[10]; const float* bl2 = (const float*)d_in[11];
  const float* Wr2 = (const float*)d_in[12]; const float* br2 = (const float*)d_in[13];
  const float* We2 = (const float*)d_in[14]; const float* att2= (const float*)d_in[15];
  const float* bc2 = (const float*)d_in[16];
  const float* Wd1 = (const float*)d_in[17]; const float* bd1 = (const float*)d_in[18];
  const float* Wd2 = (const float*)d_in[19]; const float* bd2 = (const float*)d_in[20];
  const float* Wf1 = (const float*)d_in[21]; const float* bf1 = (const float*)d_in[22];
  const float* Wf2 = (const float*)d_in[23]; const float* bf2 = (const float*)d_in[24];
  const float* Wm  = (const float*)d_in[25]; const float* bm  = (const float*)d_in[26];
  const float* Ws  = (const float*)d_in[27]; const float* bs  = (const float*)d_in[28];

  float* egoH = (float*)d_ws;   // [1024][160] fp32 = 640 KB

  gnn_two_layer_kernel<<<B_, 256, 0, stream>>>(
      x, eidx, eattr, Wl1, bl1, Wr1, br1, We1, att1, bc1,
      Wl2, bl2, Wr2, br2, We2, att2, bc2, egoH);

  mlp_head_kernel<<<B_ / 8, 256, 0, stream>>>(
      egoH, Wd1, bd1, Wd2, bd2, Wf1, bf1, Wf2, bf2, Wm, bm, Ws, bs,
      (float*)d_out);
}

// Round 2
// 451.693 us; speedup vs baseline: 1.2226x; 1.2226x over previous
//
#include <hip/hip_runtime.h>

#define B_    1024
#define NG_   32
#define F_    16
#define ED_   6
#define EG_   256
#define ET_   262144
#define H1_   5
#define C1_   80
#define HC1_  400
#define C2_   160
#define OBS_  512

#define S1_   408   // bf16 element stride for 400-wide node rows (816B, 16B-aligned)
#define MSG_S 161

typedef unsigned short ushort8v __attribute__((ext_vector_type(8)));

__device__ __forceinline__ float bf2f(unsigned short u) {
  return __uint_as_float(((unsigned int)u) << 16);
}
__device__ __forceinline__ unsigned short f2bf(float f) {
  unsigned int u = __float_as_uint(f);
  u = u + 0x7FFFu + ((u >> 16) & 1u);   // RNE
  return (unsigned short)(u >> 16);
}

// ---------------------------------------------------------------------------
// Kernel A: one block (512 threads) per graph. Both GATv2 layers in LDS;
// layer 2 evaluated only for edges into the ego node. 73 KB LDS -> 2 blocks/CU
// = 16 waves/CU.
// ---------------------------------------------------------------------------
__global__ __launch_bounds__(512, 2)
void gnn_two_layer_kernel(
    const float* __restrict__ x, const int* __restrict__ eidx,
    const float* __restrict__ eattr,
    const float* __restrict__ Wl1, const float* __restrict__ bl1,
    const float* __restrict__ Wr1, const float* __restrict__ br1,
    const float* __restrict__ We1, const float* __restrict__ att1,
    const float* __restrict__ bc1,
    const float* __restrict__ Wl2, const float* __restrict__ bl2,
    const float* __restrict__ Wr2, const float* __restrict__ br2,
    const float* __restrict__ We2, const float* __restrict__ att2,
    const float* __restrict__ bc2,
    float* __restrict__ egoH)
{
  __shared__ unsigned short xl[NG_ * S1_];    // layer-1 source transform (message), bf16
  __shared__ unsigned short xrh[NG_ * S1_];   // layer-1 target transform, then reused as h
  __shared__ float sc[EG_ * H1_];             // scores -> alpha
  __shared__ float ea[EG_ * ED_];
  __shared__ int   esrc[EG_], edst[EG_];
  __shared__ int   eorder[EG_];
  __shared__ int   bstart[NG_ + 1];
  __shared__ float msg[8 * MSG_S];
  __shared__ float out2[C2_], xr2v[C2_];
  __shared__ float sArr[8], wArr[8];
  __shared__ float mrun_s, denrun_s, scale_s;

  const int b   = blockIdx.x;
  const int tid = threadIdx.x;
  const int n0  = b * NG_;
  const int eb  = b * EG_;

  // ---------------- phase 1: loads ----------------
  if (tid < EG_) {
    esrc[tid] = eidx[eb + tid] - n0;
    edst[tid] = eidx[ET_ + eb + tid] - n0;
  }
  for (int i = tid; i < EG_ * ED_; i += 512) ea[i] = eattr[eb * ED_ + i];
  __syncthreads();

  // ---------------- phase 2: node transforms ----------------
  {
    const int n = tid & 31;
    const float* xrow = &x[(n0 + n) * F_];
    float xv[16];
#pragma unroll
    for (int q = 0; q < 4; ++q) {
      float4 t = *(const float4*)(xrow + q * 4);
      xv[q*4+0] = t.x; xv[q*4+1] = t.y; xv[q*4+2] = t.z; xv[q*4+3] = t.w;
    }
    for (int o = (tid >> 5); o < 50; o += 16) {   // 50 octs of 8 channels
      const int c = o * 8;
      ushort8v hl, hr;
#pragma unroll
      for (int u = 0; u < 8; ++u) {
        const int cc = c + u;
        float aL = bl1[cc], aR = br1[cc];
        const float* wl = &Wl1[cc * F_];
        const float* wr = &Wr1[cc * F_];
#pragma unroll
        for (int k = 0; k < 16; ++k) {
          aL = fmaf(xv[k], wl[k], aL);
          aR = fmaf(xv[k], wr[k], aR);
        }
        hl[u] = f2bf(aL);
        hr[u] = f2bf(aR);
      }
      *(ushort8v*)(&xl[n * S1_ + c])  = hl;
      *(ushort8v*)(&xrh[n * S1_ + c]) = hr;
    }
  }
  __syncthreads();

  // ---------------- phase 3: edge scores (lane pair = edge) ----------------
  {
    const int e = tid >> 1;         // 256 edges over 512 threads
    const int s = tid & 1;          // even/odd octet split within each head
    const int sl = esrc[e], dl = edst[e];
    const float e0 = ea[e*ED_+0], e1 = ea[e*ED_+1], e2 = ea[e*ED_+2];
    const float e3 = ea[e*ED_+3], e4 = ea[e*ED_+4], e5 = ea[e*ED_+5];
    const unsigned short* xlrow = &xl[sl * S1_];
    const unsigned short* xrrow = &xrh[dl * S1_];
#pragma unroll
    for (int h = 0; h < H1_; ++h) {
      float sh = 0.f;
#pragma unroll
      for (int oo = 0; oo < 5; ++oo) {
        const int c = (h * 10 + oo * 2 + s) * 8;
        ushort8v av = *(const ushort8v*)(xlrow + c);
        ushort8v rv = *(const ushort8v*)(xrrow + c);
#pragma unroll
        for (int u = 0; u < 8; ++u) {
          const int cc = c + u;
          const float* wv = &We1[cc * ED_];
          float t0 = fmaf(wv[1], e1, wv[0] * e0);
          float t1 = fmaf(wv[3], e3, wv[2] * e2);
          float t2 = fmaf(wv[5], e5, wv[4] * e4);
          float p = (bf2f(av[u]) + bf2f(rv[u])) + (t0 + (t1 + t2));
          p = (p > 0.f) ? p : 0.2f * p;
          sh = fmaf(p, att1[cc], sh);
        }
      }
      sh += __shfl_xor(sh, 1);
      if (s == 0) sc[e * H1_ + h] = sh;
    }
  }
  __syncthreads();

  // ---------------- phase 4: deterministic buckets by dst ----------------
  if (tid < NG_) {
    int cnt = 0;
    for (int e = 0; e < EG_; ++e) cnt += (edst[e] == tid);
    bstart[tid + 1] = cnt;
  }
  __syncthreads();
  if (tid == 0) {
    bstart[0] = 0;
    for (int d = 0; d < NG_; ++d) bstart[d + 1] += bstart[d];
  }
  __syncthreads();
  if (tid < NG_) {
    int p = bstart[tid];
    for (int e = 0; e < EG_; ++e)
      if (edst[e] == tid) eorder[p++] = e;
  }
  __syncthreads();

  // ---------------- phase 5: segment softmax per (dst, head) ----------------
  if (tid < NG_ * H1_) {
    const int d = tid & 31, h = tid >> 5;
    const int s0 = bstart[d], s1 = bstart[d + 1];
    float m = -INFINITY;
    for (int k = s0; k < s1; ++k) m = fmaxf(m, sc[eorder[k] * H1_ + h]);
    float den = 0.f;
    for (int k = s0; k < s1; ++k) {
      float t = expf(sc[eorder[k] * H1_ + h] - m);
      den += t;
      sc[eorder[k] * H1_ + h] = t;
    }
    const float r = 1.f / (den + 1e-16f);
    for (int k = s0; k < s1; ++k) sc[eorder[k] * H1_ + h] *= r;
  }
  __syncthreads();

  // ---------------- phase 6: aggregation, h = relu(sum alpha*msg + bc1) -----
  for (int idx = tid; idx < NG_ * 50; idx += 512) {
    const int d  = idx / 50;
    const int co = idx - d * 50;
    const int c  = co * 8;
    const int h  = c / C1_;           // oct never crosses a head (8 | 80)
    const int s0 = bstart[d], s1 = bstart[d + 1];
    float acc[8] = {0.f,0.f,0.f,0.f,0.f,0.f,0.f,0.f};
    for (int k = s0; k < s1; ++k) {
      const int e = eorder[k];
      const float al = sc[e * H1_ + h];
      ushort8v xv = *(const ushort8v*)(&xl[esrc[e] * S1_ + c]);
#pragma unroll
      for (int u = 0; u < 8; ++u) acc[u] = fmaf(al, bf2f(xv[u]), acc[u]);
    }
    ushort8v hv;
#pragma unroll
    for (int u = 0; u < 8; ++u)
      hv[u] = f2bf(fmaxf(acc[u] + bc1[c + u], 0.f));
    *(ushort8v*)(&xrh[d * S1_ + c]) = hv;   // xr dead; reuse as h
  }
  __syncthreads();

  // ---------------- phase 7: layer-2, ego node only ----------------
  const int nE = bstart[1];   // edges with local dst == 0

  if (tid < C2_) {
    float acc = br2[tid];
    const float* wr = &Wr2[tid * HC1_];
    for (int k = 0; k < HC1_; k += 8) {
      ushort8v hv = *(const ushort8v*)(&xrh[k]);      // h[ego]
      float4 w0 = *(const float4*)(wr + k);
      float4 w1 = *(const float4*)(wr + k + 4);
      acc = fmaf(bf2f(hv[0]), w0.x, acc);
      acc = fmaf(bf2f(hv[1]), w0.y, acc);
      acc = fmaf(bf2f(hv[2]), w0.z, acc);
      acc = fmaf(bf2f(hv[3]), w0.w, acc);
      acc = fmaf(bf2f(hv[4]), w1.x, acc);
      acc = fmaf(bf2f(hv[5]), w1.y, acc);
      acc = fmaf(bf2f(hv[6]), w1.z, acc);
      acc = fmaf(bf2f(hv[7]), w1.w, acc);
    }
    xr2v[tid] = acc;
    out2[tid] = 0.f;
  }
  if (tid == 0) { mrun_s = -INFINITY; denrun_s = 0.f; scale_s = 0.f; }
  __syncthreads();

  for (int ch = 0; ch < nE; ch += 8) {
    const int nc = min(8, nE - ch);
    for (int idx = tid; idx < nc * C2_; idx += 512) {
      const int j  = idx / C2_;
      const int cc = idx - j * C2_;
      const int e  = eorder[ch + j];
      const unsigned short* hrow = &xrh[esrc[e] * S1_];
      const float* wl = &Wl2[cc * HC1_];
      float acc = bl2[cc];
      for (int k = 0; k < HC1_; k += 8) {
        ushort8v hv = *(const ushort8v*)(hrow + k);
        float4 w0 = *(const float4*)(wl + k);
        float4 w1 = *(const float4*)(wl + k + 4);
        acc = fmaf(bf2f(hv[0]), w0.x, acc);
        acc = fmaf(bf2f(hv[1]), w0.y, acc);
        acc = fmaf(bf2f(hv[2]), w0.z, acc);
        acc = fmaf(bf2f(hv[3]), w0.w, acc);
        acc = fmaf(bf2f(hv[4]), w1.x, acc);
        acc = fmaf(bf2f(hv[5]), w1.y, acc);
        acc = fmaf(bf2f(hv[6]), w1.z, acc);
        acc = fmaf(bf2f(hv[7]), w1.w, acc);
      }
      msg[j * MSG_S + cc] = acc;
    }
    __syncthreads();
    if (tid < nc) {
      const int e = eorder[ch + tid];
      const float e0 = ea[e*ED_+0], e1 = ea[e*ED_+1], e2 = ea[e*ED_+2];
      const float e3 = ea[e*ED_+3], e4 = ea[e*ED_+4], e5 = ea[e*ED_+5];
      float s = 0.f;
      for (int cc = 0; cc < C2_; ++cc) {
        const float* wv = &We2[cc * ED_];
        float t0 = fmaf(wv[1], e1, wv[0] * e0);
        float t1 = fmaf(wv[3], e3, wv[2] * e2);
        float t2 = fmaf(wv[5], e5, wv[4] * e4);
        float p = msg[tid * MSG_S + cc] + xr2v[cc] + (t0 + (t1 + t2));
        p = (p > 0.f) ? p : 0.2f * p;
        s = fmaf(p, att2[cc], s);
      }
      sArr[tid] = s;
    }
    __syncthreads();
    if (tid == 0) {
      float m = mrun_s;
      for (int j = 0; j < nc; ++j) m = fmaxf(m, sArr[j]);
      const float scl = expf(mrun_s - m);    // expf(-inf)=0 on first chunk
      float den = denrun_s * scl;
      for (int j = 0; j < nc; ++j) { float w = expf(sArr[j] - m); wArr[j] = w; den += w; }
      mrun_s = m; denrun_s = den; scale_s = scl;
    }
    __syncthreads();
    if (tid < C2_) {
      float o = out2[tid] * scale_s;
      for (int j = 0; j < nc; ++j) o = fmaf(wArr[j], msg[j * MSG_S + tid], o);
      out2[tid] = o;
    }
    __syncthreads();
  }

  if (tid < C2_) {
    const float v = out2[tid] / (denrun_s + 1e-16f) + bc2[tid];
    egoH[b * C2_ + tid] = fmaxf(v, 0.f);
  }
}

// ---------------------------------------------------------------------------
// Kernel B: dense head + MLP. 256 blocks x 512 threads, 4 graphs per block,
// batch-vectorized accumulators (one weight load feeds 2 graphs).
// ---------------------------------------------------------------------------
__global__ __launch_bounds__(512, 2)
void mlp_head_kernel(
    const float* __restrict__ egoH,
    const float* __restrict__ Wd1, const float* __restrict__ bd1,
    const float* __restrict__ Wd2, const float* __restrict__ bd2,
    const float* __restrict__ Wf1, const float* __restrict__ bf1,
    const float* __restrict__ Wf2, const float* __restrict__ bf2,
    const float* __restrict__ Wm,  const float* __restrict__ bm,
    const float* __restrict__ Ws,  const float* __restrict__ bs,
    float* __restrict__ out)
{
  __shared__ float hE[4 * C2_];
  __shared__ float t1[4 * NG_];
  __shared__ float dbuf[4 * OBS_];
  __shared__ float f1b[4 * 256];
  __shared__ float f2b[4 * 256];

  const int g0  = blockIdx.x * 4;
  const int tid = threadIdx.x;

  for (int i = tid; i < 4 * C2_; i += 512) hE[i] = egoH[g0 * C2_ + i];
  __syncthreads();

  // t1 = ego @ Wd1^T + bd1   [4][32]
  if (tid < 4 * NG_) {
    const int g = tid >> 5, o = tid & 31;
    float acc = bd1[o];
    const float* w  = &Wd1[o * C2_];
    const float* hp = &hE[g * C2_];
    for (int k = 0; k < C2_; k += 4) {
      float4 hv = *(const float4*)(hp + k);
      float4 wv = *(const float4*)(w + k);
      acc = fmaf(hv.x, wv.x, acc); acc = fmaf(hv.y, wv.y, acc);
      acc = fmaf(hv.z, wv.z, acc); acc = fmaf(hv.w, wv.w, acc);
    }
    t1[tid] = acc;
  }
  __syncthreads();

  // d = tanh(t1 @ Wd2^T + bd2)   [4][512]
  for (int idx = tid; idx < 4 * OBS_; idx += 512) {
    const int g = idx >> 9, o = idx & 511;
    float acc = bd2[o];
    const float* w  = &Wd2[o * NG_];
    const float* tp = &t1[g * NG_];
#pragma unroll
    for (int k = 0; k < NG_; k += 4) {
      float4 tv = *(const float4*)(tp + k);
      float4 wv = *(const float4*)(w + k);
      acc = fmaf(tv.x, wv.x, acc); acc = fmaf(tv.y, wv.y, acc);
      acc = fmaf(tv.z, wv.z, acc); acc = fmaf(tv.w, wv.w, acc);
    }
    dbuf[idx] = tanhf(acc);
  }
  __syncthreads();

  // f1 = relu(d @ Wf1^T + bf1)  [4][256]; thread=(o, graph-pair)
  {
    const int o = tid & 255, gg = tid >> 8;
    const float* w  = &Wf1[o * OBS_];
    const float* dA = &dbuf[(gg * 2 + 0) * OBS_];
    const float* dB = &dbuf[(gg * 2 + 1) * OBS_];
    float a0 = bf1[o], a1 = a0;
#pragma unroll 2
    for (int k = 0; k < OBS_; k += 4) {
      float4 wv = *(const float4*)(w + k);
      float4 xA = *(const float4*)(dA + k);
      float4 xB = *(const float4*)(dB + k);
      a0 = fmaf(xA.x, wv.x, a0); a0 = fmaf(xA.y, wv.y, a0);
      a0 = fmaf(xA.z, wv.z, a0); a0 = fmaf(xA.w, wv.w, a0);
      a1 = fmaf(xB.x, wv.x, a1); a1 = fmaf(xB.y, wv.y, a1);
      a1 = fmaf(xB.z, wv.z, a1); a1 = fmaf(xB.w, wv.w, a1);
    }
    f1b[(gg * 2 + 0) * 256 + o] = fmaxf(a0, 0.f);
    f1b[(gg * 2 + 1) * 256 + o] = fmaxf(a1, 0.f);
  }
  __syncthreads();

  // f2 = relu(f1 @ Wf2^T + bf2)  [4][256]
  {
    const int o = tid & 255, gg = tid >> 8;
    const float* w  = &Wf2[o * 256];
    const float* dA = &f1b[(gg * 2 + 0) * 256];
    const float* dB = &f1b[(gg * 2 + 1) * 256];
    float a0 = bf2[o], a1 = a0;
#pragma unroll 2
    for (int k = 0; k < 256; k += 4) {
      float4 wv = *(const float4*)(w + k);
      float4 xA = *(const float4*)(dA + k);
      float4 xB = *(const float4*)(dB + k);
      a0 = fmaf(xA.x, wv.x, a0); a0 = fmaf(xA.y, wv.y, a0);
      a0 = fmaf(xA.z, wv.z, a0); a0 = fmaf(xA.w, wv.w, a0);
      a1 = fmaf(xB.x, wv.x, a1); a1 = fmaf(xB.y, wv.y, a1);
      a1 = fmaf(xB.z, wv.z, a1); a1 = fmaf(xB.w, wv.w, a1);
    }
    f2b[(gg * 2 + 0) * 256 + o] = fmaxf(a0, 0.f);
    f2b[(gg * 2 + 1) * 256 + o] = fmaxf(a1, 0.f);
  }
  __syncthreads();

  // heads: mean, log_std — 4 graphs x 2 actions x {mean, std}
  if (tid < 16) {
    const int g  = tid >> 2;
    const int a  = (tid >> 1) & 1;
    const int hm = tid & 1;
    const float* fp = &f2b[g * 256];
    const float* w  = hm ? &Ws[a * 256] : &Wm[a * 256];
    float acc = hm ? bs[a] : bm[a];
    for (int k = 0; k < 256; ++k) acc = fmaf(fp[k], w[k], acc);
    if (hm == 0) out[(g0 + g) * 2 + a] = acc;
    else         out[2048 + (g0 + g) * 2 + a] = -5.0f + 3.5f * (tanhf(acc) + 1.0f);
  }
}

extern "C" void kernel_launch(void* const* d_in, const int* in_sizes, int n_in,
                              void* d_out, int out_size, void* d_ws, size_t ws_size,
                              hipStream_t stream) {
  const float* x     = (const float*)d_in[0];
  const int*   eidx  = (const int*)d_in[1];
  const float* eattr = (const float*)d_in[2];
  const float* Wl1 = (const float*)d_in[3];  const float* bl1 = (const float*)d_in[4];
  const float* Wr1 = (const float*)d_in[5];  const float* br1 = (const float*)d_in[6];
  const float* We1 = (const float*)d_in[7];  const float* att1= (const float*)d_in[8];
  const float* bc1 = (const float*)d_in[9];
  const float* Wl2 = (const float*)d_in[10]; const float* bl2 = (const float*)d_in[11];
  const float* Wr2 = (const float*)d_in[12]; const float* br2 = (const float*)d_in[13];
  const float* We2 = (const float*)d_in[14]; const float* att2= (const float*)d_in[15];
  const float* bc2 = (const float*)d_in[16];
  const float* Wd1 = (const float*)d_in[17]; const float* bd1 = (const float*)d_in[18];
  const float* Wd2 = (const float*)d_in[19]; const float* bd2 = (const float*)d_in[20];
  const float* Wf1 = (const float*)d_in[21]; const float* bf1 = (const float*)d_in[22];
  const float* Wf2 = (const float*)d_in[23]; const float* bf2 = (const float*)d_in[24];
  const float* Wm  = (const float*)d_in[25]; const float* bm  = (const float*)d_in[26];
  const float* Ws  = (const float*)d_in[27]; const float* bs  = (const float*)d_in[28];

  float* egoH = (float*)d_ws;   // [1024][160] fp32 = 640 KB

  gnn_two_layer_kernel<<<B_, 512, 0, stream>>>(
      x, eidx, eattr, Wl1, bl1, Wr1, br1, We1, att1, bc1,
      Wl2, bl2, Wr2, br2, We2, att2, bc2, egoH);

  mlp_head_kernel<<<B_ / 4, 512, 0, stream>>>(
      egoH, Wd1, bd1, Wd2, bd2, Wf1, bf1, Wf2, bf2, Wm, bm, Ws, bs,
      (float*)d_out);
}